// Round 17
// baseline (61.911 us; speedup 1.0000x reference)
//
#include <hip/hip_runtime.h>
#include <stdint.h>

#define N_ROWS 32768
#define DIM    256
#define KCODES 8192
#define KSPLIT 8
#define KPS    1024                 /* codes per split */
#define NPH    64                  /* phases (16 codes) per split */
#define BM     128                 /* 2 waves x 64 rows */
#define THREADS 128

typedef int   v4i __attribute__((ext_vector_type(4)));
typedef int   v8i __attribute__((ext_vector_type(8)));
typedef float v4f __attribute__((ext_vector_type(4)));

// ---- fp4 e2m1 encode (values 0,.5,1,1.5,2,3,4,6; saturating) ---------------
__device__ __forceinline__ uint32_t enc1(float f) {
  float a = fabsf(f);
  uint32_t s = (__float_as_uint(f) >> 28) & 0x8u;
  uint32_t m = a < 0.75f ? (a < 0.25f ? 0u : 1u)
             : a < 1.75f ? (a < 1.25f ? 2u : 3u)
             : a < 3.5f  ? (a < 2.5f  ? 4u : 5u)
             : (a < 5.0f ? 6u : 7u);
  return s | m;
}

// ---- Kernel P: fused prep, COALESCED. blocks [0,4096): x ; [4096,5120): w ---
// thread -> (row, word-slot): 32 consecutive threads cover one row's 1KB
// contiguously (2 interleaved float4 loads), 1 u32 store each.
// frag-major u32 layout: rg(row>>4)*512 + kh*256 + (kq*16 + (row&15))*4 + wi,
// covering k = kh*128 + kq*32 + wi*8 + nib (LSB-first nibbles).
__global__ void kprep(const float* __restrict__ x, const float* __restrict__ wgt,
                      uint32_t* __restrict__ x4, uint32_t* __restrict__ wb4,
                      float* __restrict__ xsq, float* __restrict__ bb) {
  const int b = blockIdx.x;
  const float* src;
  uint32_t* dst;
  float* sq;
  float scale;
  int gid;
  if (b < 4096) { gid = b * 256 + threadIdx.x; src = x; dst = x4; sq = xsq; scale = 1.f; }
  else { gid = (b - 4096) * 256 + threadIdx.x; src = wgt; dst = wb4; sq = bb; scale = -32768.f; }
  const int row = gid >> 5, ws = gid & 31;
  const int kh = ws >> 4, kq = (ws >> 2) & 3, wi = ws & 3;
  const float* s = src + (size_t)row * DIM + kh * 128 + kq * 32 + wi * 8;
  const float4 v0 = *(const float4*)s;
  const float4 v1 = *(const float4*)(s + 4);
  float sa = v0.x * v0.x;
  sa = fmaf(v0.y, v0.y, sa); sa = fmaf(v0.z, v0.z, sa); sa = fmaf(v0.w, v0.w, sa);
  sa = fmaf(v1.x, v1.x, sa); sa = fmaf(v1.y, v1.y, sa);
  sa = fmaf(v1.z, v1.z, sa); sa = fmaf(v1.w, v1.w, sa);
  uint32_t u = enc1(v0.x * scale)        | (enc1(v0.y * scale) << 4)
             | (enc1(v0.z * scale) << 8) | (enc1(v0.w * scale) << 12)
             | (enc1(v1.x * scale) << 16)| (enc1(v1.y * scale) << 20)
             | (enc1(v1.z * scale) << 24)| (enc1(v1.w * scale) << 28);
  const int rg = row >> 4, r = row & 15;
  dst[(size_t)rg * 512 + kh * 256 + (kq * 16 + r) * 4 + wi] = u;
  sa += __shfl_xor(sa, 1, 64);
  sa += __shfl_xor(sa, 2, 64);
  sa += __shfl_xor(sa, 4, 64);
  sa += __shfl_xor(sa, 8, 64);
  sa += __shfl_xor(sa, 16, 64);
  if ((threadIdx.x & 31) == 0) sq[row] = sa;
}

// ---- Kernel B: fp4 MFMA argmin, zero LDS / zero barriers -------------------
// 2 waves x 64 register-resident rows (PINNED via opaque asm so the compiler
// cannot rematerialize the loads inside the loop); B streams L2->regs,
// 2-phase register prefetch; constant C-operand; 10-bit tag in mantissa
// noise bits; min_u32 argmin.
__global__ __launch_bounds__(THREADS, 3) void kmain(
    const uint32_t* __restrict__ x4, const uint32_t* __restrict__ wb4,
    uint64_t* __restrict__ cand) {
  const int bx = blockIdx.x, sp = blockIdx.y;
  const int t = threadIdx.x;
  const int wv = t >> 6, l = t & 63;
  const int col = l & 15, q = l >> 4;
  const int rgb = bx * 8 + wv * 4;           // 16-row-group base
  const int k0 = sp * KPS;

  // A: 64 rows -> 4 packed v8i {kh0|kh1} + shuffled copies (kh1 in low half)
  v8i afr[4], afrH[4];
#pragma unroll
  for (int rf = 0; rf < 4; ++rf) {
    const uint32_t* ap = x4 + (size_t)(rgb + rf) * 512 + l * 4;
    v8i a;
    *(v4i*)&a = *(const v4i*)ap;
    *((v4i*)&a + 1) = *(const v4i*)(ap + 256);
    afr[rf] = a;
    afrH[rf] = __builtin_shufflevector(a, a, 4, 5, 6, 7, 4, 5, 6, 7);
  }
  // pin: values become asm outputs -> not rematerializable, stay in VGPRs
#pragma unroll
  for (int rf = 0; rf < 4; ++rf)
    asm volatile("" : "+v"(afr[rf]), "+v"(afrH[rf]));

  uint32_t mp[4][4];
#pragma unroll
  for (int rf = 0; rf < 4; ++rf)
#pragma unroll
    for (int j = 0; j < 4; ++j) mp[rf][j] = 0xFFFFFFFFu;

  const v4f accc = {16384.f, 16384.f, 16384.f, 16384.f};  // hoisted C-operand
  const uint32_t* bs = wb4 + (size_t)(sp * NPH) * 512 + l * 4;

  auto loadB = [&](v8i& B0, v8i& B1, int gi) {
    const uint32_t* p = bs + (size_t)gi * 512;
    *(v4i*)&B0 = *(const v4i*)p;             // kh0 in low half
    *(v4i*)&B1 = *(const v4i*)(p + 256);     // kh1 in low half
  };
  auto phase = [&](int gi, const v8i& B0, const v8i& B1) {
    const uint32_t tag = ((uint32_t)gi << 4) | (uint32_t)col;  // local code id
#pragma unroll
    for (int rf = 0; rf < 4; ++rf) {
      v4f acc = __builtin_amdgcn_mfma_scale_f32_16x16x128_f8f6f4(
          afr[rf], B0, accc, 4, 4, 0, 127, 0, 127);
      acc = __builtin_amdgcn_mfma_scale_f32_16x16x128_f8f6f4(
          afrH[rf], B1, acc, 4, 4, 0, 127, 0, 127);
#pragma unroll
      for (int j = 0; j < 4; ++j) {
        uint32_t pv = __float_as_uint(acc[j]) | tag;
        mp[rf][j] = pv < mp[rf][j] ? pv : mp[rf][j];
      }
    }
  };

  v8i b0a = {}, b1a = {}, b0b = {}, b1b = {};
  loadB(b0a, b1a, 0);
  loadB(b0b, b1b, 1);
  for (int gi = 0; gi < NPH; gi += 2) {
    phase(gi, b0a, b1a);
    loadB(b0a, b1a, gi + 2);                 // unconditional prefetch (stays in ws)
    phase(gi + 1, b0b, b1b);
    loadB(b0b, b1b, gi + 3);
  }

  // cross-lane argmin over 16 code-columns, write candidates
#pragma unroll
  for (int rf = 0; rf < 4; ++rf)
#pragma unroll
    for (int j = 0; j < 4; ++j) {
      uint32_t pv = mp[rf][j];
#pragma unroll
      for (int o = 1; o < 16; o <<= 1) {
        uint32_t ov = (uint32_t)__shfl_xor((int)pv, o, 64);
        pv = ov < pv ? ov : pv;
      }
      if (col == 0) {
        int row = bx * BM + wv * 64 + rf * 16 + q * 4 + j;
        cand[(size_t)row * KSPLIT + sp] =
            ((uint64_t)pv << 13) | (uint32_t)(k0 + (pv & 1023u));
      }
    }
}

// ---- Kernel C: combine splits, gather out, loss from score+tables ----------
__global__ void kout(const float* __restrict__ wgt, const uint64_t* __restrict__ cand,
                     const float* __restrict__ xsq, const float* __restrict__ bb,
                     float* __restrict__ out, float* __restrict__ partial) {
  const int t = threadIdx.x;
  const int rb = blockIdx.x * 64;
  __shared__ int sk[64];
  if (t < 64) {
    const uint64_t* c = cand + (size_t)(rb + t) * KSPLIT;
    uint64_t P = c[0];
#pragma unroll
    for (int i = 1; i < KSPLIT; ++i) P = c[i] < P ? c[i] : P;
    int k = (int)(P & 8191u);
    sk[t] = k;
    // score = 16384*(1 - 2*x.w_q); row loss = |x|^2 - 2 x.q + |q|^2
    float sc = __uint_as_float((uint32_t)(P >> 13) & 0xFFFFFC00u);
    float lr = xsq[rb + t] + sc * 0.00006103515625f - 1.0f + bb[k];
    for (int o = 32; o; o >>= 1) lr += __shfl_down(lr, o, 64);
    if (t == 0) partial[blockIdx.x] = lr;
  }
  __syncthreads();
#pragma unroll 4
  for (int r = 0; r < 64; ++r) {
    out[(size_t)(rb + r) * DIM + t] = wgt[(size_t)sk[r] * DIM + t];
  }
}

// ---- Kernel D: final loss ---------------------------------------------------
__global__ void kloss(const float* __restrict__ partial, float* __restrict__ lossout) {
  const int t = threadIdx.x;
  float s = partial[t] + partial[t + 256];
  for (int o = 32; o; o >>= 1) s += __shfl_down(s, o, 64);
  __shared__ float red[4];
  if ((t & 63) == 0) red[t >> 6] = s;
  __syncthreads();
  if (t == 0) lossout[0] = 1.5f * (red[0] + red[1] + red[2] + red[3]) /
                           (float)((size_t)N_ROWS * DIM);
}

extern "C" void kernel_launch(void* const* d_in, const int* in_sizes, int n_in,
                              void* d_out, int out_size, void* d_ws, size_t ws_size,
                              hipStream_t stream) {
  const float* x   = (const float*)d_in[0];
  const float* wgt = (const float*)d_in[1];
  float* out = (float*)d_out;
  uint8_t* ws = (uint8_t*)d_ws;
  uint32_t* x4      = (uint32_t*)ws;                        // 4 MB
  uint32_t* wb4     = (uint32_t*)(ws + 4194304u);           // 1 MB
  float*    xsq     = (float*)(ws + 5242880u);              // 128 KB
  float*    bb      = (float*)(ws + 5373952u);              // 32 KB
  uint64_t* cand    = (uint64_t*)(ws + 5406720u);           // 2 MB
  float*    partial = (float*)(ws + 7503872u);              // 2 KB

  kprep<<<5120, 256, 0, stream>>>(x, wgt, x4, wb4, xsq, bb);
  dim3 g(N_ROWS / BM, KSPLIT);
  kmain<<<g, THREADS, 0, stream>>>(x4, wb4, cand);
  kout<<<N_ROWS / 64, 256, 0, stream>>>(wgt, cand, xsq, bb, out, partial);
  kloss<<<1, 256, 0, stream>>>(partial, out + (size_t)N_ROWS * DIM);
}

// Round 18
// 60.050 us; speedup vs baseline: 1.0310x; 1.0310x over previous
//
#include <hip/hip_runtime.h>
#include <stdint.h>

#define N_ROWS 32768
#define DIM    256
#define KCODES 8192
#define KSPLIT 8
#define KPS    1024                 /* codes per split */
#define NPH    64                  /* phases (16 codes) per split */
#define BM     128                 /* 2 waves x 64 rows */
#define THREADS 128

typedef int   v4i __attribute__((ext_vector_type(4)));
typedef int   v8i __attribute__((ext_vector_type(8)));
typedef float v4f __attribute__((ext_vector_type(4)));

// ---- fp4 e2m1 encode (values 0,.5,1,1.5,2,3,4,6; saturating) ---------------
__device__ __forceinline__ uint32_t enc1(float f) {
  float a = fabsf(f);
  uint32_t s = (__float_as_uint(f) >> 28) & 0x8u;
  uint32_t m = a < 0.75f ? (a < 0.25f ? 0u : 1u)
             : a < 1.75f ? (a < 1.25f ? 2u : 3u)
             : a < 3.5f  ? (a < 2.5f  ? 4u : 5u)
             : (a < 5.0f ? 6u : 7u);
  return s | m;
}

// ---- Kernel P: fused prep, COALESCED. blocks [0,4096): x ; [4096,5120): w ---
// thread -> (row, word-slot): 32 consecutive threads cover one row's 1KB
// contiguously (2 interleaved float4 loads), 1 u32 store each.
// frag-major u32 layout: rg(row>>4)*512 + kh*256 + (kq*16 + (row&15))*4 + wi,
// covering k = kh*128 + kq*32 + wi*8 + nib (LSB-first nibbles).
__global__ void kprep(const float* __restrict__ x, const float* __restrict__ wgt,
                      uint32_t* __restrict__ x4, uint32_t* __restrict__ wb4,
                      float* __restrict__ xsq, float* __restrict__ bb) {
  const int b = blockIdx.x;
  const float* src;
  uint32_t* dst;
  float* sq;
  float scale;
  int gid;
  if (b < 4096) { gid = b * 256 + threadIdx.x; src = x; dst = x4; sq = xsq; scale = 1.f; }
  else { gid = (b - 4096) * 256 + threadIdx.x; src = wgt; dst = wb4; sq = bb; scale = -32768.f; }
  const int row = gid >> 5, ws = gid & 31;
  const int kh = ws >> 4, kq = (ws >> 2) & 3, wi = ws & 3;
  const float* s = src + (size_t)row * DIM + kh * 128 + kq * 32 + wi * 8;
  const float4 v0 = *(const float4*)s;
  const float4 v1 = *(const float4*)(s + 4);
  float sa = v0.x * v0.x;
  sa = fmaf(v0.y, v0.y, sa); sa = fmaf(v0.z, v0.z, sa); sa = fmaf(v0.w, v0.w, sa);
  sa = fmaf(v1.x, v1.x, sa); sa = fmaf(v1.y, v1.y, sa);
  sa = fmaf(v1.z, v1.z, sa); sa = fmaf(v1.w, v1.w, sa);
  uint32_t u = enc1(v0.x * scale)        | (enc1(v0.y * scale) << 4)
             | (enc1(v0.z * scale) << 8) | (enc1(v0.w * scale) << 12)
             | (enc1(v1.x * scale) << 16)| (enc1(v1.y * scale) << 20)
             | (enc1(v1.z * scale) << 24)| (enc1(v1.w * scale) << 28);
  const int rg = row >> 4, r = row & 15;
  dst[(size_t)rg * 512 + kh * 256 + (kq * 16 + r) * 4 + wi] = u;
  sa += __shfl_xor(sa, 1, 64);
  sa += __shfl_xor(sa, 2, 64);
  sa += __shfl_xor(sa, 4, 64);
  sa += __shfl_xor(sa, 8, 64);
  sa += __shfl_xor(sa, 16, 64);
  if ((threadIdx.x & 31) == 0) sq[row] = sa;
}

// ---- Kernel B: fp4 MFMA argmin, zero LDS / zero barriers -------------------
// 2 waves x 64 register-resident rows; B streams L2->regs with a STRUCTURAL
// 4-deep software pipeline: loads issue 4 phases before use, one
// sched_barrier(0) per phase pins [MFMA gi][load gi+4][fence] so the compiler
// cannot sink prefetches to their use site. Constant C-operand; 10-bit tag in
// mantissa noise bits; min_u32 argmin.
__global__ __launch_bounds__(THREADS, 3) void kmain(
    const uint32_t* __restrict__ x4, const uint32_t* __restrict__ wb4,
    uint64_t* __restrict__ cand) {
  const int bx = blockIdx.x, sp = blockIdx.y;
  const int t = threadIdx.x;
  const int wv = t >> 6, l = t & 63;
  const int col = l & 15, q = l >> 4;
  const int rgb = bx * 8 + wv * 4;           // 16-row-group base
  const int k0 = sp * KPS;

  // A: 64 rows -> 4 packed v8i {kh0|kh1} + shuffled copies (kh1 in low half)
  v8i afr[4], afrH[4];
#pragma unroll
  for (int rf = 0; rf < 4; ++rf) {
    const uint32_t* ap = x4 + (size_t)(rgb + rf) * 512 + l * 4;
    v8i a;
    *(v4i*)&a = *(const v4i*)ap;
    *((v4i*)&a + 1) = *(const v4i*)(ap + 256);
    afr[rf] = a;
    afrH[rf] = __builtin_shufflevector(a, a, 4, 5, 6, 7, 4, 5, 6, 7);
  }

  uint32_t mp[4][4];
#pragma unroll
  for (int rf = 0; rf < 4; ++rf)
#pragma unroll
    for (int j = 0; j < 4; ++j) mp[rf][j] = 0xFFFFFFFFu;

  const v4f accc = {16384.f, 16384.f, 16384.f, 16384.f};  // hoisted C-operand
  const uint32_t* bs = wb4 + (size_t)(sp * NPH) * 512 + l * 4;

  auto loadB = [&](v8i& B0, v8i& B1, const uint32_t* p) {
    *(v4i*)&B0 = *(const v4i*)p;             // kh0 in low half (imm off 0)
    *(v4i*)&B1 = *(const v4i*)(p + 256);     // kh1 in low half (imm off 1KB)
  };
  auto phase = [&](int gi, const v8i& B0, const v8i& B1) {
    const uint32_t tag = ((uint32_t)gi << 4) | (uint32_t)col;  // local code id
#pragma unroll
    for (int rf = 0; rf < 4; ++rf) {
      v4f acc = __builtin_amdgcn_mfma_scale_f32_16x16x128_f8f6f4(
          afr[rf], B0, accc, 4, 4, 0, 127, 0, 127);
      acc = __builtin_amdgcn_mfma_scale_f32_16x16x128_f8f6f4(
          afrH[rf], B1, acc, 4, 4, 0, 127, 0, 127);
#pragma unroll
      for (int j = 0; j < 4; ++j) {
        uint32_t pv = __float_as_uint(acc[j]) | tag;
        mp[rf][j] = pv < mp[rf][j] ? pv : mp[rf][j];
      }
    }
  };

  v8i b0a = {}, b1a = {}, b0b = {}, b1b = {};
  v8i b0c = {}, b1c = {}, b0d = {}, b1d = {};
  loadB(b0a, b1a, bs);
  loadB(b0b, b1b, bs + 512);
  loadB(b0c, b1c, bs + 1024);
  loadB(b0d, b1d, bs + 1536);
  const uint32_t* p = bs + 2048;             // phase gi+4 data; +512/phase
  for (int gi = 0; gi < NPH; gi += 4) {
    // [MFMA+argmin gi][issue loads gi+4][fence] -> 3+ phase load-use distance
    phase(gi + 0, b0a, b1a);
    loadB(b0a, b1a, p); p += 512;            // overruns last 4 phases: lands
    __builtin_amdgcn_sched_barrier(0);       // in ws slack past wb4 (harmless)
    phase(gi + 1, b0b, b1b);
    loadB(b0b, b1b, p); p += 512;
    __builtin_amdgcn_sched_barrier(0);
    phase(gi + 2, b0c, b1c);
    loadB(b0c, b1c, p); p += 512;
    __builtin_amdgcn_sched_barrier(0);
    phase(gi + 3, b0d, b1d);
    loadB(b0d, b1d, p); p += 512;
    __builtin_amdgcn_sched_barrier(0);
  }

  // cross-lane argmin over 16 code-columns, write candidates
#pragma unroll
  for (int rf = 0; rf < 4; ++rf)
#pragma unroll
    for (int j = 0; j < 4; ++j) {
      uint32_t pv = mp[rf][j];
#pragma unroll
      for (int o = 1; o < 16; o <<= 1) {
        uint32_t ov = (uint32_t)__shfl_xor((int)pv, o, 64);
        pv = ov < pv ? ov : pv;
      }
      if (col == 0) {
        int row = bx * BM + wv * 64 + rf * 16 + q * 4 + j;
        cand[(size_t)row * KSPLIT + sp] =
            ((uint64_t)pv << 13) | (uint32_t)(k0 + (pv & 1023u));
      }
    }
}

// ---- Kernel C: combine splits, gather out, loss from score+tables ----------
__global__ void kout(const float* __restrict__ wgt, const uint64_t* __restrict__ cand,
                     const float* __restrict__ xsq, const float* __restrict__ bb,
                     float* __restrict__ out, float* __restrict__ partial) {
  const int t = threadIdx.x;
  const int rb = blockIdx.x * 64;
  __shared__ int sk[64];
  if (t < 64) {
    const uint64_t* c = cand + (size_t)(rb + t) * KSPLIT;
    uint64_t P = c[0];
#pragma unroll
    for (int i = 1; i < KSPLIT; ++i) P = c[i] < P ? c[i] : P;
    int k = (int)(P & 8191u);
    sk[t] = k;
    // score = 16384*(1 - 2*x.w_q); row loss = |x|^2 - 2 x.q + |q|^2
    float sc = __uint_as_float((uint32_t)(P >> 13) & 0xFFFFFC00u);
    float lr = xsq[rb + t] + sc * 0.00006103515625f - 1.0f + bb[k];
    for (int o = 32; o; o >>= 1) lr += __shfl_down(lr, o, 64);
    if (t == 0) partial[blockIdx.x] = lr;
  }
  __syncthreads();
#pragma unroll 4
  for (int r = 0; r < 64; ++r) {
    out[(size_t)(rb + r) * DIM + t] = wgt[(size_t)sk[r] * DIM + t];
  }
}

// ---- Kernel D: final loss ---------------------------------------------------
__global__ void kloss(const float* __restrict__ partial, float* __restrict__ lossout) {
  const int t = threadIdx.x;
  float s = partial[t] + partial[t + 256];
  for (int o = 32; o; o >>= 1) s += __shfl_down(s, o, 64);
  __shared__ float red[4];
  if ((t & 63) == 0) red[t >> 6] = s;
  __syncthreads();
  if (t == 0) lossout[0] = 1.5f * (red[0] + red[1] + red[2] + red[3]) /
                           (float)((size_t)N_ROWS * DIM);
}

extern "C" void kernel_launch(void* const* d_in, const int* in_sizes, int n_in,
                              void* d_out, int out_size, void* d_ws, size_t ws_size,
                              hipStream_t stream) {
  const float* x   = (const float*)d_in[0];
  const float* wgt = (const float*)d_in[1];
  float* out = (float*)d_out;
  uint8_t* ws = (uint8_t*)d_ws;
  uint32_t* x4      = (uint32_t*)ws;                        // 4 MB
  uint32_t* wb4     = (uint32_t*)(ws + 4194304u);           // 1 MB (+64KB slack)
  float*    xsq     = (float*)(ws + 5308416u);              // 128 KB
  float*    bb      = (float*)(ws + 5439488u);              // 32 KB
  uint64_t* cand    = (uint64_t*)(ws + 5472256u);           // 2 MB
  float*    partial = (float*)(ws + 7569408u);              // 2 KB

  kprep<<<5120, 256, 0, stream>>>(x, wgt, x4, wb4, xsq, bb);
  dim3 g(N_ROWS / BM, KSPLIT);
  kmain<<<g, THREADS, 0, stream>>>(x4, wb4, cand);
  kout<<<N_ROWS / 64, 256, 0, stream>>>(wgt, cand, xsq, bb, out, partial);
  kloss<<<1, 256, 0, stream>>>(partial, out + (size_t)N_ROWS * DIM);
}